// Round 11
// baseline (285.707 us; speedup 1.0000x reference)
//
#include <hip/hip_runtime.h>
#include <hip/hip_bf16.h>

namespace {

constexpr int kB = 2, kS = 512, kE = 1024, kH = 16, kD = 64;
constexpr int kM = kB * kS;   // 1024
constexpr int kBH = kB * kH;  // 32
constexpr int kSP = 524;      // padded LDS score row stride (f32)
constexpr unsigned kNB = 1024;  // grid size == 256 CU x 4 blocks (must match!)

typedef short bf16x8 __attribute__((ext_vector_type(8)));
typedef float f32x4 __attribute__((ext_vector_type(4)));

__device__ __forceinline__ unsigned short f2bf(float f) {
  __hip_bfloat16 h = __float2bfloat16(f);
  unsigned short u;
  __builtin_memcpy(&u, &h, 2);
  return u;
}
__device__ __forceinline__ float bf2f(unsigned short u) {
  unsigned int x = (unsigned int)u << 16;
  float f;
  __builtin_memcpy(&f, &x, 4);
  return f;
}

// Cache-op-minimal device barrier (r9-proven): relaxed polls (no per-poll
// buffer_inv), one release fence (wbl2) + one acquire fence (inv) per block.
__device__ __forceinline__ void grid_barrier(unsigned* base, int slot) {
  __syncthreads();
  if (threadIdx.x == 0) {
    unsigned* cnt = base + slot * 64;
    unsigned* flg = base + slot * 64 + 32;
    __builtin_amdgcn_fence(__ATOMIC_RELEASE, "agent");
    unsigned arrived = __hip_atomic_fetch_add(cnt, 1u, __ATOMIC_RELAXED,
                                              __HIP_MEMORY_SCOPE_AGENT) + 1u;
    if (arrived == kNB) {
      __hip_atomic_store(flg, 1u, __ATOMIC_RELAXED, __HIP_MEMORY_SCOPE_AGENT);
    } else {
      int spins = 0;
      while (__hip_atomic_load(flg, __ATOMIC_RELAXED,
                               __HIP_MEMORY_SCOPE_AGENT) == 0u) {
        __builtin_amdgcn_s_sleep(16);
        if (++spins > 1000000) break;  // fail visibly instead of hanging
      }
    }
    __builtin_amdgcn_fence(__ATOMIC_ACQUIRE, "agent");
  }
  __syncthreads();
}

// ---------------- generic 32x32 MFMA tile: C = A * B^T (per-wave) -----------
__device__ __forceinline__ void mfma_tile_32x32(
    const unsigned short* __restrict__ A, int lda,
    const unsigned short* __restrict__ Bm, int ldb,
    int row0, int col0, int K, f32x4 acc[2][2]) {
  const int lane = threadIdx.x & 63;
  const int r = lane & 15;
  const int ko = (lane >> 4) * 8;
  const unsigned short* a0 = A + (size_t)(row0 + r) * lda + ko;
  const unsigned short* a1 = a0 + 16 * (size_t)lda;
  const unsigned short* b0 = Bm + (size_t)(col0 + r) * ldb + ko;
  const unsigned short* b1 = b0 + 16 * (size_t)ldb;
  for (int kk = 0; kk < K; kk += 32) {
    bf16x8 af0 = *reinterpret_cast<const bf16x8*>(a0 + kk);
    bf16x8 af1 = *reinterpret_cast<const bf16x8*>(a1 + kk);
    bf16x8 bg0 = *reinterpret_cast<const bf16x8*>(b0 + kk);
    bf16x8 bg1 = *reinterpret_cast<const bf16x8*>(b1 + kk);
    acc[0][0] = __builtin_amdgcn_mfma_f32_16x16x32_bf16(af0, bg0, acc[0][0], 0, 0, 0);
    acc[0][1] = __builtin_amdgcn_mfma_f32_16x16x32_bf16(af0, bg1, acc[0][1], 0, 0, 0);
    acc[1][0] = __builtin_amdgcn_mfma_f32_16x16x32_bf16(af1, bg0, acc[1][0], 0, 0, 0);
    acc[1][1] = __builtin_amdgcn_mfma_f32_16x16x32_bf16(af1, bg1, acc[1][1], 0, 0, 0);
  }
}

// store helper for 32x32 projection tiles
__device__ __forceinline__ void store_proj_tile(
    f32x4 acc[2][2], int row0, int col0, int which,  // 0=q/k-layout, 1=vT
    unsigned short* __restrict__ dstQK, unsigned short* __restrict__ dstVT) {
  const int lane = threadIdx.x & 63;
#pragma unroll
  for (int ri = 0; ri < 2; ++ri)
#pragma unroll
    for (int ci = 0; ci < 2; ++ci)
#pragma unroll
      for (int r = 0; r < 4; ++r) {
        int i = row0 + 16 * ri + 4 * (lane >> 4) + r;  // b*512+s
        int j = col0 + 16 * ci + (lane & 15);          // h*64+d
        int b = i >> 9, s = i & 511, h = j >> 6, d = j & 63;
        unsigned short val = f2bf(acc[ri][ci][r]);
        if (which)
          dstVT[(((size_t)(b * kH + h) * kD) + d) * kS + s] = val;
        else
          dstQK[(((size_t)(b * kH + h) * kS) + s) * kD + d] = val;
      }
}

// ==================== single fused persistent kernel ====================
// 1024 blocks x 256 threads, 33.5 KB LDS -> exactly 4 blocks/CU co-resident.
__global__ __launch_bounds__(256, 4) void fused_kernel(
    const float* __restrict__ qf, const float* __restrict__ kf,
    const float* __restrict__ vf, const float* __restrict__ p,
    const float* __restrict__ Wqf, const float* __restrict__ Wkf,
    const float* __restrict__ Wvf, const float* __restrict__ Wof,
    unsigned short* __restrict__ cvt,  // 7 consecutive 1M-elem bf16 regions
    unsigned short* __restrict__ qh, unsigned short* __restrict__ kh,
    unsigned short* __restrict__ vhT, unsigned short* __restrict__ qp,
    unsigned short* __restrict__ att, float* __restrict__ out,
    unsigned* __restrict__ ctr) {
  __shared__ float S[16 * kSP];  // 33,536 B
  const int bid = blockIdx.x;
  const int t = threadIdx.x;
  const int w = t >> 6;
  const int lane = t & 63;
  const size_t nME = (size_t)kM * kE;

  // ---- phase A: f32 -> bf16 for q,k,v,Wq,Wk,Wv,Wo (1 float4/thread/tensor) --
  {
    const int idx = bid * 256 + t;  // 0..262143
#pragma unroll
    for (int tt = 0; tt < 7; ++tt) {
      const float* src = tt == 0 ? qf : tt == 1 ? kf : tt == 2 ? vf
                       : tt == 3 ? Wqf : tt == 4 ? Wkf : tt == 5 ? Wvf : Wof;
      unsigned short* dst = cvt + (size_t)tt * nME;
      float4 v4 = *reinterpret_cast<const float4*>(src + (size_t)idx * 4);
      ushort4 o;
      o.x = f2bf(v4.x); o.y = f2bf(v4.y); o.z = f2bf(v4.z); o.w = f2bf(v4.w);
      *reinterpret_cast<ushort4*>(dst + (size_t)idx * 4) = o;
    }
  }
  grid_barrier(ctr, 0);

  // ---- phase B: proj_q — 1024 per-wave 32x32 units, 1 unit/block ----------
  {
    if (w == (bid >> 8)) {  // spread busy waves across SIMDs
      const int unit = bid;
      const int row0 = (unit >> 5) * 32, col0 = (unit & 31) * 32;
      f32x4 acc[2][2] = {};
      mfma_tile_32x32(cvt, kE, cvt + 3 * nME, kE, row0, col0, kE, acc);
      store_proj_tile(acc, row0, col0, 0, qh, nullptr);
    }
  }
  grid_barrier(ctr, 1);

  // ---- phase C: qp (1 (b,s)/block, BW stream) + proj_k/v (waves 0,1) ------
  {
    float (*qsh)[kD] = reinterpret_cast<float (*)[kD]>(S);
    const int bs = bid;  // 0..1023
    const int b = bs >> 9, s = bs & 511;
    {
      int h = t >> 4, d4 = (t & 15) * 4;
      const unsigned short* qr =
          qh + (((size_t)(b * kH + h) * kS) + s) * kD + d4;
      ushort4 uq = *reinterpret_cast<const ushort4*>(qr);
      qsh[h][d4 + 0] = bf2f(uq.x);
      qsh[h][d4 + 1] = bf2f(uq.y);
      qsh[h][d4 + 2] = bf2f(uq.z);
      qsh[h][d4 + 3] = bf2f(uq.w);
    }
    __syncthreads();
    const int g = lane >> 4, fi = lane & 15;
#pragma unroll
    for (int j = 0; j < 4; ++j) {
      const int hh = w * 4 + j;
      const f32x4* p4 = reinterpret_cast<const f32x4*>(p) +
                        ((size_t)(bs * kH + hh) << 10);
      f32x4 acc = {0.f, 0.f, 0.f, 0.f};
#pragma unroll
      for (int iter = 0; iter < 16; ++iter) {
        f32x4 pv = p4[iter * 64 + lane];  // 1KB contiguous per wave-load
        float qv = qsh[hh][iter * 4 + g];
        acc[0] += qv * pv[0];
        acc[1] += qv * pv[1];
        acc[2] += qv * pv[2];
        acc[3] += qv * pv[3];
      }
#pragma unroll
      for (int m = 16; m <= 32; m <<= 1) {
        acc[0] += __shfl_xor(acc[0], m);
        acc[1] += __shfl_xor(acc[1], m);
        acc[2] += __shfl_xor(acc[2], m);
        acc[3] += __shfl_xor(acc[3], m);
      }
      if (g == 0) {
        ushort4 o;
        o.x = f2bf(acc[0]); o.y = f2bf(acc[1]);
        o.z = f2bf(acc[2]); o.w = f2bf(acc[3]);
        *reinterpret_cast<ushort4*>(
            qp + (((size_t)(b * kH + hh) * kS) + s) * kD + fi * 4) = o;
      }
    }
    // proj_k/v: 2048 per-wave 32x32 units on waves 0,1 of every block
    if (w < 2) {
      const int id = bid * 2 + w;      // 0..2047
      const int which = id >> 10;      // 0=k, 1=v
      const int tile = id & 1023;
      const int row0 = (tile >> 5) * 32, col0 = (tile & 31) * 32;
      const unsigned short* A = cvt + (which ? 2 : 1) * nME;
      const unsigned short* W = cvt + (which ? 5 : 4) * nME;
      f32x4 acc[2][2] = {};
      mfma_tile_32x32(A, kE, W, kE, row0, col0, kE, acc);
      store_proj_tile(acc, row0, col0, which, kh, vhT);
    }
  }
  grid_barrier(ctr, 2);

  // ---- phase D: fused scores->softmax->PV, 16 q-rows per block ------------
  {
    const int bh = bid >> 5;   // 0..31
    const int bx = bid & 31;   // 16-row tile
    const int b = bh >> 4, h = bh & 15;
    const int row0 = bx * 16;
    const int ncol = row0 + 16;
    const int nct = ((bx >> 1) + 1) * 2;  // 16-col tiles up to 32-boundary
    const int g = lane >> 4, c = lane & 15;

    const unsigned short* Abase = qp + (size_t)bh * kS * kD;
    const unsigned short* Kbase = kh + (size_t)bh * kS * kD;

    bf16x8 qa0 = *reinterpret_cast<const bf16x8*>(
        Abase + (size_t)(row0 + c) * kD + g * 8);
    bf16x8 qa1 = *reinterpret_cast<const bf16x8*>(
        Abase + (size_t)(row0 + c) * kD + 32 + g * 8);

    for (int ct = w; ct < nct; ct += 4) {
      const int col0 = ct * 16;
      const unsigned short* kr = Kbase + (size_t)(col0 + c) * kD + g * 8;
      bf16x8 kb0 = *reinterpret_cast<const bf16x8*>(kr);
      bf16x8 kb1 = *reinterpret_cast<const bf16x8*>(kr + 32);
      f32x4 sacc = {};
      sacc = __builtin_amdgcn_mfma_f32_16x16x32_bf16(qa0, kb0, sacc, 0, 0, 0);
      sacc = __builtin_amdgcn_mfma_f32_16x16x32_bf16(qa1, kb1, sacc, 0, 0, 0);
#pragma unroll
      for (int r = 0; r < 4; ++r) {
        int il = 4 * g + r;            // local row 0..15
        int jg = col0 + c;             // global col
        float val = sacc[r] * 0.125f;
        if (jg > row0 + il) val = -1e9f;  // causal mask
        S[il * kSP + jg] = val;
      }
    }
    __syncthreads();

    // softmax: rows w*4 .. w*4+3 (writes all 512 cols -> zeros beyond ncol)
#pragma unroll
    for (int rr = 0; rr < 4; ++rr) {
      const int i = w * 4 + rr;
      float v[8];
      float m = -1e30f;
#pragma unroll
      for (int ii = 0; ii < 8; ++ii) {
        int j = lane + 64 * ii;
        v[ii] = (j < ncol) ? S[i * kSP + j] : -1e30f;
        m = fmaxf(m, v[ii]);
      }
#pragma unroll
      for (int off = 32; off; off >>= 1) m = fmaxf(m, __shfl_xor(m, off));
      float e[8], sum = 0.f;
#pragma unroll
      for (int ii = 0; ii < 8; ++ii) {
        e[ii] = __expf(v[ii] - m);
        sum += e[ii];
      }
#pragma unroll
      for (int off = 32; off; off >>= 1) sum += __shfl_xor(sum, off);
      const float inv = 1.0f / sum;
#pragma unroll
      for (int ii = 0; ii < 8; ++ii) S[i * kSP + lane + 64 * ii] = e[ii] * inv;
    }
    __syncthreads();

    // PV: wave w -> d in [16w, 16w+16)
    const int d0 = w * 16;
    const unsigned short* Vbase = vhT + (size_t)(bh * kD + d0 + c) * kS;
    f32x4 oacc = {};
    const int nk = (bx >> 1) + 1;  // 32-wide k-steps over [0, ncol32)
    for (int ks = 0; ks < nk; ++ks) {
      const int kb = ks * 32;
      bf16x8 vfrag = *reinterpret_cast<const bf16x8*>(Vbase + kb + g * 8);
      const float* sp = &S[c * kSP + kb + g * 8];
      float4 x0 = *reinterpret_cast<const float4*>(sp);
      float4 x1 = *reinterpret_cast<const float4*>(sp + 4);
      bf16x8 pa;
      pa[0] = (short)f2bf(x0.x); pa[1] = (short)f2bf(x0.y);
      pa[2] = (short)f2bf(x0.z); pa[3] = (short)f2bf(x0.w);
      pa[4] = (short)f2bf(x1.x); pa[5] = (short)f2bf(x1.y);
      pa[6] = (short)f2bf(x1.z); pa[7] = (short)f2bf(x1.w);
      oacc = __builtin_amdgcn_mfma_f32_16x16x32_bf16(pa, vfrag, oacc, 0, 0, 0);
    }
#pragma unroll
    for (int r = 0; r < 4; ++r) {
      int s = row0 + 4 * g + r;
      int d = d0 + c;
      att[((size_t)(b * kS + s) * kE) + h * kD + d] = f2bf(oacc[r]);
    }
  }
  grid_barrier(ctr, 3);

  // ---- phase E: out = att @ Wo^T — 1024 per-wave 32x32 units --------------
  {
    if (w == (bid >> 8)) {
      const int unit = bid;
      const int row0 = (unit >> 5) * 32, col0 = (unit & 31) * 32;
      f32x4 acc[2][2] = {};
      mfma_tile_32x32(att, kE, cvt + 6 * nME, kE, row0, col0, kE, acc);
#pragma unroll
      for (int ri = 0; ri < 2; ++ri)
#pragma unroll
        for (int ci = 0; ci < 2; ++ci)
#pragma unroll
          for (int r = 0; r < 4; ++r) {
            int i = row0 + 16 * ri + 4 * (lane >> 4) + r;
            int j = col0 + 16 * ci + (lane & 15);
            out[(size_t)i * kE + j] = acc[ri][ci][r];
          }
    }
  }
}

}  // namespace

extern "C" void kernel_launch(void* const* d_in, const int* in_sizes, int n_in,
                              void* d_out, int out_size, void* d_ws,
                              size_t ws_size, hipStream_t stream) {
  const float* q = (const float*)d_in[0];
  const float* k = (const float*)d_in[1];
  const float* v = (const float*)d_in[2];
  const float* p = (const float*)d_in[3];
  const float* Wq = (const float*)d_in[5];
  const float* Wk = (const float*)d_in[6];
  const float* Wv = (const float*)d_in[7];
  const float* Wo = (const float*)d_in[8];
  float* out = (float*)d_out;

  char* ws = (char*)d_ws;
  size_t off = 0;
  auto alloc = [&](size_t bytes) {
    void* ptr = ws + off;
    off += (bytes + 255) & ~(size_t)255;
    return ptr;
  };
  const size_t nME = (size_t)kM * kE;  // 1,048,576
  // 7 consecutive 2MB bf16 regions: q,k,v,Wq,Wk,Wv,Wo
  unsigned short* cvtB = (unsigned short*)alloc(nME * 2 * 7);
  unsigned short* qhB = (unsigned short*)alloc(nME * 2);
  unsigned short* khB = (unsigned short*)alloc(nME * 2);
  unsigned short* vhTB = (unsigned short*)alloc(nME * 2);
  unsigned short* qpB = (unsigned short*)alloc(nME * 2);
  unsigned short* attB = (unsigned short*)alloc(nME * 2);
  unsigned* ctr = (unsigned*)alloc(4096);

  hipMemsetAsync(ctr, 0, 4096, stream);
  fused_kernel<<<kNB, 256, 0, stream>>>(q, k, v, p, Wq, Wk, Wv, Wo, cvtB, qhB,
                                        khB, vhTB, qpB, attB, out, ctr);
}